// Round 1
// baseline (183.934 us; speedup 1.0000x reference)
//
#include <hip/hip_runtime.h>

// ---------------------------------------------------------------------------
// CrossRNN: embed-gather -> 2-layer Elman RNN (relu) -> row/col cross -> dot
// B=4 R=64 C=64 S=32 V=30000 E=H=128 L=2   N = B*R*C = 16384 sequences
//
// Pipeline:
//  k_t1   : T1[v,h] = embed[v,:]·W_ih[0][h,:] + b_ih[0][h]      (30000x128 f32)
//  k_rnn  : fused 2-layer RNN over S=32 steps, MFMA bf16, weights in regs.
//           emits s1[n] = h2_31·pred_W[0:128], s2[n] = h2_31·pred_W[128:256]
//  k_final: out[b,r,c] = s1 + rowsum(s2) + colsum(s2) - 2*s2 + pred_b
// ---------------------------------------------------------------------------

typedef __attribute__((ext_vector_type(8))) short short8;
typedef __attribute__((ext_vector_type(4))) float f32x4;

#define Hd 128
#define Sd 32
#define NSEQ 16
#define VROWS 30000

__device__ __forceinline__ unsigned short f2b(float f) {
  unsigned int u = __float_as_uint(f);
  u += 0x7FFFu + ((u >> 16) & 1u);   // round-to-nearest-even
  return (unsigned short)(u >> 16);
}

__device__ __forceinline__ f32x4 mfma16(short8 a, short8 b, f32x4 c) {
  return __builtin_amdgcn_mfma_f32_16x16x32_bf16(a, b, c, 0, 0, 0);
}

// load 8 consecutive f32 (32B aligned) and convert to a bf16 fragment
__device__ __forceinline__ short8 load_row8_bf16(const float* __restrict__ p) {
  const float4* q = reinterpret_cast<const float4*>(p);
  float4 a = q[0], b = q[1];
  short8 s;
  s[0] = (short)f2b(a.x); s[1] = (short)f2b(a.y);
  s[2] = (short)f2b(a.z); s[3] = (short)f2b(a.w);
  s[4] = (short)f2b(b.x); s[5] = (short)f2b(b.y);
  s[6] = (short)f2b(b.z); s[7] = (short)f2b(b.w);
  return s;
}

// read 4 A-fragments (one per 32-wide K-tile) from swizzled LDS h-buffer
// buffer layout: row-major [16][128] bf16 (256B rows), byte ^= ((row&7)<<4)
__device__ __forceinline__ void read_frags(short8* dst, const unsigned short* buf,
                                           int rowA, int kb) {
#pragma unroll
  for (int kt = 0; kt < 4; ++kt) {
    int off = rowA * 256 + (((kt * 64) + kb) ^ ((rowA & 7) << 4));
    dst[kt] = *reinterpret_cast<const short8*>(
        reinterpret_cast<const char*>(buf) + off);
  }
}

// write h (post-relu, f32 -> bf16) from C-fragments into swizzled LDS buffer
__device__ __forceinline__ void write_h(unsigned short* buf, const f32x4* C,
                                        const int* col, int lg) {
#pragma unroll
  for (int nti = 0; nti < 2; ++nti) {
#pragma unroll
    for (int r = 0; r < 4; ++r) {
      int row = lg * 4 + r;
      int off = row * 256 + (((col[nti] * 2)) ^ ((row & 7) << 4));
      *reinterpret_cast<unsigned short*>(reinterpret_cast<char*>(buf) + off) =
          f2b(C[nti][r]);
    }
  }
}

// ---------------------------------------------------------------------------
// K1: T1 = embed @ W_ih[0]^T + b_ih[0]
// grid: ceil(30000/64) blocks of 256 threads; each wave = one 16-row M-tile
// ---------------------------------------------------------------------------
__global__ __launch_bounds__(256, 2) void k_t1(const float* __restrict__ embed,
                                               const float* __restrict__ W_ih,
                                               const float* __restrict__ b_ih,
                                               float* __restrict__ T1) {
  const int tid = threadIdx.x, lane = tid & 63, wid = tid >> 6;
  const int l15 = lane & 15, lg = lane >> 4;
  const int vtile = blockIdx.x * 4 + wid;

  short8 Bf[8][4];
#pragma unroll
  for (int nt = 0; nt < 8; ++nt) {
    int h = nt * 16 + l15;
#pragma unroll
    for (int kt = 0; kt < 4; ++kt)
      Bf[nt][kt] = load_row8_bf16(W_ih + h * Hd + kt * 32 + lg * 8);
  }

  int v = vtile * 16 + l15;
  if (v >= VROWS) v = VROWS - 1;
  short8 Af[4];
#pragma unroll
  for (int kt = 0; kt < 4; ++kt)
    Af[kt] = load_row8_bf16(embed + v * Hd + kt * 32 + lg * 8);

  f32x4 C[8];
#pragma unroll
  for (int nt = 0; nt < 8; ++nt) {
    float bi = b_ih[nt * 16 + l15];
    C[nt] = (f32x4){bi, bi, bi, bi};
  }
#pragma unroll
  for (int kt = 0; kt < 4; ++kt) {
#pragma unroll
    for (int nt = 0; nt < 8; ++nt) C[nt] = mfma16(Af[kt], Bf[nt][kt], C[nt]);
  }

  const int vout = vtile * 16 + lg * 4;
#pragma unroll
  for (int nt = 0; nt < 8; ++nt) {
    int colh = nt * 16 + l15;
#pragma unroll
    for (int r = 0; r < 4; ++r) {
      int row = vout + r;
      if (row < VROWS) T1[row * Hd + colh] = C[nt][r];
    }
  }
}

// ---------------------------------------------------------------------------
// K2: fused 2-layer RNN. grid 1024 blocks x 256 threads; 16 sequences/block.
// Wave ns (0..3) owns output columns [ns*32, ns*32+32).
// ---------------------------------------------------------------------------
__global__ __launch_bounds__(256, 2) void k_rnn(
    const int* __restrict__ x, const float* __restrict__ T1,
    const float* __restrict__ W_ih, const float* __restrict__ W_hh,
    const float* __restrict__ b_ih, const float* __restrict__ b_hh,
    const float* __restrict__ pred_W, float* __restrict__ sbuf) {
  __shared__ alignas(16) unsigned short h1buf[NSEQ * Hd];  // 4KB swizzled bf16
  __shared__ alignas(16) unsigned short h2buf[NSEQ * Hd];  // 4KB
  __shared__ int xs[NSEQ * Sd];                            // 2KB
  __shared__ float sred[4][16][2];

  const int tid = threadIdx.x, lane = tid & 63, ns = tid >> 6;
  const int l15 = lane & 15, lg = lane >> 4;
  const int seq0 = blockIdx.x * NSEQ;
  const int rowA = l15;        // A-fragment row
  const int kb = lg * 16;      // A-fragment byte offset within 64B k-tile

  // stage this block's x indices (contiguous 512 ints)
  xs[tid] = x[seq0 * Sd + tid];
  xs[tid + 256] = x[seq0 * Sd + 256 + tid];

  // per-wave weight fragments (B-operand: B[k][j] = W[j][k])
  short8 Wh0f[2][4], Wi1f[2][4], Wh1f[2][4];
  int col[2];
  float bh0v[2], bsumv[2], pw1v[2], pw2v[2];
#pragma unroll
  for (int nti = 0; nti < 2; ++nti) {
    int c = ns * 32 + nti * 16 + l15;
    col[nti] = c;
#pragma unroll
    for (int kt = 0; kt < 4; ++kt) {
      Wh0f[nti][kt] = load_row8_bf16(W_hh + c * Hd + kt * 32 + lg * 8);
      Wi1f[nti][kt] = load_row8_bf16(W_ih + Hd * Hd + c * Hd + kt * 32 + lg * 8);
      Wh1f[nti][kt] = load_row8_bf16(W_hh + Hd * Hd + c * Hd + kt * 32 + lg * 8);
    }
    bh0v[nti] = b_hh[c];
    bsumv[nti] = b_ih[Hd + c] + b_hh[Hd + c];
    pw1v[nti] = pred_W[c];
    pw2v[nti] = pred_W[Hd + c];
  }
  __syncthreads();

  short8 h1f[4], h2f[4];
  f32x4 C1[2], C2[2];
  float t1v[2][4];

  // ---- t = 0 : h1_0 = relu(T1[x0] + bh0) ; h2_0 = relu(bsum + Wi1·h1_0)
#pragma unroll
  for (int r = 0; r < 4; ++r) {
    int idx = xs[(lg * 4 + r) * Sd + 0];
    t1v[0][r] = T1[idx * Hd + col[0]];
    t1v[1][r] = T1[idx * Hd + col[1]];
  }
#pragma unroll
  for (int nti = 0; nti < 2; ++nti) {
#pragma unroll
    for (int r = 0; r < 4; ++r)
      C1[nti][r] = fmaxf(t1v[nti][r] + bh0v[nti], 0.f);
  }
  write_h(h1buf, C1, col, lg);
  __syncthreads();
  read_frags(h1f, h1buf, rowA, kb);

#pragma unroll
  for (int nti = 0; nti < 2; ++nti)
    C2[nti] = (f32x4){bsumv[nti], bsumv[nti], bsumv[nti], bsumv[nti]};
#pragma unroll
  for (int kt = 0; kt < 4; ++kt) {
#pragma unroll
    for (int nti = 0; nti < 2; ++nti)
      C2[nti] = mfma16(h1f[kt], Wi1f[nti][kt], C2[nti]);
  }
#pragma unroll
  for (int nti = 0; nti < 2; ++nti) {
#pragma unroll
    for (int r = 0; r < 4; ++r) C2[nti][r] = fmaxf(C2[nti][r], 0.f);
  }
  write_h(h2buf, C2, col, lg);
  __syncthreads();
  read_frags(h2f, h2buf, rowA, kb);

  // ---- t = 1..31
  for (int t = 1; t < Sd; ++t) {
    // gather next input projection early (overlaps MFMA)
#pragma unroll
    for (int r = 0; r < 4; ++r) {
      int idx = xs[(lg * 4 + r) * Sd + t];
      t1v[0][r] = T1[idx * Hd + col[0]];
      t1v[1][r] = T1[idx * Hd + col[1]];
    }
    // layer 1: C1 = bh0 + Wh0·h1_{t-1}, then += T1 gather, relu
#pragma unroll
    for (int nti = 0; nti < 2; ++nti)
      C1[nti] = (f32x4){bh0v[nti], bh0v[nti], bh0v[nti], bh0v[nti]};
#pragma unroll
    for (int kt = 0; kt < 4; ++kt) {
#pragma unroll
      for (int nti = 0; nti < 2; ++nti)
        C1[nti] = mfma16(h1f[kt], Wh0f[nti][kt], C1[nti]);
    }
#pragma unroll
    for (int nti = 0; nti < 2; ++nti) {
#pragma unroll
      for (int r = 0; r < 4; ++r)
        C1[nti][r] = fmaxf(C1[nti][r] + t1v[nti][r], 0.f);
    }
    write_h(h1buf, C1, col, lg);
    __syncthreads();
    read_frags(h1f, h1buf, rowA, kb);

    // layer 2: C2 = bsum + Wi1·h1_t + Wh1·h2_{t-1}, relu
#pragma unroll
    for (int nti = 0; nti < 2; ++nti)
      C2[nti] = (f32x4){bsumv[nti], bsumv[nti], bsumv[nti], bsumv[nti]};
#pragma unroll
    for (int kt = 0; kt < 4; ++kt) {
#pragma unroll
      for (int nti = 0; nti < 2; ++nti) {
        C2[nti] = mfma16(h1f[kt], Wi1f[nti][kt], C2[nti]);
        C2[nti] = mfma16(h2f[kt], Wh1f[nti][kt], C2[nti]);
      }
    }
#pragma unroll
    for (int nti = 0; nti < 2; ++nti) {
#pragma unroll
      for (int r = 0; r < 4; ++r) C2[nti][r] = fmaxf(C2[nti][r], 0.f);
    }
    write_h(h2buf, C2, col, lg);
    __syncthreads();
    read_frags(h2f, h2buf, rowA, kb);
  }

  // ---- epilogue: s1 = h2_31·pW[0:128], s2 = h2_31·pW[128:256]
  float p1[4], p2[4];
#pragma unroll
  for (int r = 0; r < 4; ++r) {
    p1[r] = C2[0][r] * pw1v[0] + C2[1][r] * pw1v[1];
    p2[r] = C2[0][r] * pw2v[0] + C2[1][r] * pw2v[1];
  }
#pragma unroll
  for (int m = 1; m < 16; m <<= 1) {
#pragma unroll
    for (int r = 0; r < 4; ++r) {
      p1[r] += __shfl_xor(p1[r], m);
      p2[r] += __shfl_xor(p2[r], m);
    }
  }
  if (l15 == 0) {
#pragma unroll
    for (int r = 0; r < 4; ++r) {
      sred[ns][lg * 4 + r][0] = p1[r];
      sred[ns][lg * 4 + r][1] = p2[r];
    }
  }
  __syncthreads();
  if (tid < 32) {
    int nl = tid >> 1, st = tid & 1;
    float v = sred[0][nl][st] + sred[1][nl][st] + sred[2][nl][st] +
              sred[3][nl][st];
    sbuf[st * 16384 + seq0 + nl] = v;
  }
}

// ---------------------------------------------------------------------------
// K3: out[b,r,c] = s1 + rowsum_c(s2) + colsum_r(s2) - 2*s2 + pred_b
// ---------------------------------------------------------------------------
__global__ __launch_bounds__(1024) void k_final(const float* __restrict__ sbuf,
                                                const float* __restrict__ pred_b,
                                                float* __restrict__ out) {
  __shared__ float s2s[64][65];
  __shared__ float rowS[64], colS[64];
  const int b = blockIdx.x, tid = threadIdx.x;
  const float* s1g = sbuf + b * 4096;
  const float* s2g = sbuf + 16384 + b * 4096;
#pragma unroll
  for (int i = 0; i < 4; ++i) {
    int j = tid + i * 1024;
    s2s[j >> 6][j & 63] = s2g[j];
  }
  __syncthreads();
  if (tid < 64) {
    float s = 0.f;
    for (int c = 0; c < 64; ++c) s += s2s[tid][c];
    rowS[tid] = s;
  } else if (tid < 128) {
    int c = tid - 64;
    float s = 0.f;
    for (int r = 0; r < 64; ++r) s += s2s[r][c];
    colS[c] = s;
  }
  __syncthreads();
  const float pb = pred_b[0];
#pragma unroll
  for (int i = 0; i < 4; ++i) {
    int j = tid + i * 1024;
    int r = j >> 6, c = j & 63;
    out[b * 4096 + j] = s1g[j] + rowS[r] + colS[c] - 2.f * s2s[r][c] + pb;
  }
}

// ---------------------------------------------------------------------------
extern "C" void kernel_launch(void* const* d_in, const int* in_sizes, int n_in,
                              void* d_out, int out_size, void* d_ws,
                              size_t ws_size, hipStream_t stream) {
  const int* x = (const int*)d_in[0];
  const float* embed = (const float*)d_in[1];
  const float* W_ih = (const float*)d_in[2];
  const float* W_hh = (const float*)d_in[3];
  const float* b_ih = (const float*)d_in[4];
  const float* b_hh = (const float*)d_in[5];
  const float* pred_W = (const float*)d_in[6];
  const float* pred_b = (const float*)d_in[7];

  float* T1 = (float*)d_ws;                  // 30000*128 f32 = 15.36 MB
  float* sbuf = T1 + VROWS * Hd;             // 2*16384 f32
  float* out = (float*)d_out;

  k_t1<<<(VROWS + 63) / 64, 256, 0, stream>>>(embed, W_ih, b_ih, T1);
  k_rnn<<<16384 / NSEQ, 256, 0, stream>>>(x, T1, W_ih, W_hh, b_ih, b_hh,
                                          pred_W, sbuf);
  k_final<<<4, 1024, 0, stream>>>(sbuf, pred_b, out);
}